// Round 1
// baseline (4270.425 us; speedup 1.0000x reference)
//
#include <hip/hip_runtime.h>
#include <math.h>

// Problem constants (match reference)
#define N_NODES 100000
#define N_EDGES 500000
#define N_META  2
#define DIM     64
#define HID     128
#define BATCH   8192

__device__ __forceinline__ float wave_reduce_sum(float v) {
    #pragma unroll
    for (int off = 32; off; off >>= 1) v += __shfl_xor(v, off);
    return v;
}

// feat = h @ W[m]; el = feat @ al[m]; er = feat @ ar[m]
__global__ void feat_kernel(const float* __restrict__ h, const float* __restrict__ W,
                            const float* __restrict__ al, const float* __restrict__ ar,
                            float* __restrict__ feat, float* __restrict__ el,
                            float* __restrict__ er, int N) {
    const int m = blockIdx.y;
    __shared__ float Wl[64 * 64];
    __shared__ float alv_s[64], arv_s[64];
    const float* Wm = W + m * 64 * 64;
    for (int i = threadIdx.x; i < 4096; i += blockDim.x) Wl[i] = Wm[i];
    if (threadIdx.x < 64) {
        alv_s[threadIdx.x] = al[m * 64 + threadIdx.x];
        arv_s[threadIdx.x] = ar[m * 64 + threadIdx.x];
    }
    __syncthreads();
    const int lane = threadIdx.x & 63;
    const int wave = threadIdx.x >> 6;
    const int wpb  = blockDim.x >> 6;
    const float alv = alv_s[lane], arv = arv_s[lane];
    for (int row = blockIdx.x * wpb + wave; row < N; row += gridDim.x * wpb) {
        float hv = h[row * 64 + lane];
        float f = 0.f;
        #pragma unroll
        for (int k = 0; k < 64; ++k) f += __shfl(hv, k) * Wl[k * 64 + lane];
        feat[(size_t)(m * N + row) * 64 + lane] = f;
        float e1 = wave_reduce_sum(f * alv);
        float e2 = wave_reduce_sum(f * arv);
        if (lane == 0) { el[m * N + row] = e1; er[m * N + row] = e2; }
    }
}

__global__ void hist_kernel(const int* __restrict__ dst, int* __restrict__ counts, int E) {
    for (int i = blockIdx.x * blockDim.x + threadIdx.x; i < E; i += gridDim.x * blockDim.x)
        atomicAdd(&counts[dst[i]], 1);
}

// exclusive scan, single block of 1024 threads
__global__ void scan_kernel(const int* __restrict__ counts, int* __restrict__ offsets, int n) {
    __shared__ int sh[1024];
    __shared__ int carry_s;
    if (threadIdx.x == 0) carry_s = 0;
    __syncthreads();
    for (int base = 0; base < n; base += 1024) {
        int i = base + (int)threadIdx.x;
        int v = (i < n) ? counts[i] : 0;
        sh[threadIdx.x] = v;
        __syncthreads();
        int c = carry_s;
        for (int off = 1; off < 1024; off <<= 1) {
            int t = (threadIdx.x >= (unsigned)off) ? sh[threadIdx.x - off] : 0;
            __syncthreads();
            sh[threadIdx.x] += t;
            __syncthreads();
        }
        if (i < n) offsets[i] = c + sh[threadIdx.x] - v;
        __syncthreads();
        if (threadIdx.x == 0) carry_s = c + sh[1023];
        __syncthreads();
    }
    if (threadIdx.x == 0) offsets[n] = carry_s;
}

__global__ void copy_int(const int* __restrict__ a, int* __restrict__ b, int n) {
    for (int i = blockIdx.x * blockDim.x + threadIdx.x; i < n; i += gridDim.x * blockDim.x)
        b[i] = a[i];
}

__global__ void scatter_kernel(const int* __restrict__ src, const int* __restrict__ dst,
                               int* __restrict__ cursor, int* __restrict__ esrc, int E) {
    for (int i = blockIdx.x * blockDim.x + threadIdx.x; i < E; i += gridDim.x * blockDim.x) {
        int d = dst[i];
        int pos = atomicAdd(&cursor[d], 1);
        esrc[pos] = src[i];
    }
}

// one wave per dst node: edge-softmax + weighted aggregate + elu(+b)
__global__ void agg_kernel(const float* __restrict__ feat, const float* __restrict__ el,
                           const float* __restrict__ er, const float* __restrict__ bvec,
                           const int* __restrict__ offsets, const int* __restrict__ esrc,
                           float* __restrict__ z, int N) {
    const int lane = threadIdx.x & 63;
    const int wave = threadIdx.x >> 6;
    const int wpb  = blockDim.x >> 6;
    const float bv = bvec[lane];
    for (int node = blockIdx.x * wpb + wave; node < N; node += gridDim.x * wpb) {
        int beg = offsets[node], end = offsets[node + 1];
        float erd = er[node];
        float mx = -INFINITY;
        for (int i = beg; i < end; ++i) {
            int s = esrc[i];
            float e = el[s] + erd;
            e = (e >= 0.f) ? e : 0.2f * e;
            mx = fmaxf(mx, e);
        }
        float l = 0.f, acc = 0.f;
        for (int i = beg; i < end; ++i) {
            int s = esrc[i];
            float e = el[s] + erd;
            e = (e >= 0.f) ? e : 0.2f * e;
            float ex = expf(e - mx);
            l += ex;
            acc += ex * feat[(size_t)s * 64 + lane];
        }
        float o = acc / (l + 1e-9f);
        float zz = o + bv;
        zz = (zz > 0.f) ? zz : expm1f(zz);
        z[(size_t)node * 64 + lane] = zz;
    }
}

// wsum[m] += sum_n tanh(z[m,n] @ W1 + b1) @ W2
__global__ void sem_kernel(const float* __restrict__ z, const float* __restrict__ W1,
                           const float* __restrict__ b1, const float* __restrict__ W2,
                           float* __restrict__ wsum, int N) {
    const int m = blockIdx.y;
    __shared__ float W1l[64 * 128];
    __shared__ float b1l[128], W2l[128];
    for (int i = threadIdx.x; i < 64 * 128; i += blockDim.x) W1l[i] = W1[i];
    if (threadIdx.x < 128) { b1l[threadIdx.x] = b1[threadIdx.x]; W2l[threadIdx.x] = W2[threadIdx.x]; }
    __syncthreads();
    const int lane = threadIdx.x & 63;
    const int wave = threadIdx.x >> 6;
    const int wpb  = blockDim.x >> 6;
    float local = 0.f;
    for (int row = blockIdx.x * wpb + wave; row < N; row += gridDim.x * wpb) {
        float zv = z[(size_t)(m * N + row) * 64 + lane];
        float t0 = b1l[lane], t1 = b1l[64 + lane];
        #pragma unroll
        for (int k = 0; k < 64; ++k) {
            float zk = __shfl(zv, k);
            t0 += zk * W1l[k * 128 + lane];
            t1 += zk * W1l[k * 128 + 64 + lane];
        }
        local += tanhf(t0) * W2l[lane] + tanhf(t1) * W2l[64 + lane];
    }
    local = wave_reduce_sum(local);
    if (lane == 0) atomicAdd(&wsum[m], local);
}

__global__ void beta_kernel(const float* __restrict__ wsum, float* __restrict__ beta, float invN) {
    if (threadIdx.x == 0 && blockIdx.x == 0) {
        for (int t = 0; t < 2; ++t) {
            float w0 = wsum[t * 2] * invN, w1 = wsum[t * 2 + 1] * invN;
            float mx = fmaxf(w0, w1);
            float e0 = expf(w0 - mx), e1 = expf(w1 - mx);
            float s = e0 + e1;
            beta[t * 2] = e0 / s; beta[t * 2 + 1] = e1 / s;
        }
    }
}

// gather + semantic combine + proj + relu + layernorm, only for indexed rows
__global__ void out_kernel(const int* __restrict__ uidx, const int* __restrict__ iidx,
                           const int* __restrict__ nidx,
                           const float* __restrict__ z_u, const float* __restrict__ z_i,
                           const float* __restrict__ beta,
                           const float* __restrict__ userW, const float* __restrict__ userb,
                           const float* __restrict__ itemW, const float* __restrict__ itemb,
                           const float* __restrict__ ln_g, const float* __restrict__ ln_b,
                           float* __restrict__ out, int N, int B) {
    const int g = blockIdx.y;  // 0: user[uidx], 1: item[iidx], 2: item[nidx]
    __shared__ float Wl[4096];
    __shared__ float btl[64], gl[64], lbl[64];
    __shared__ float betal[2];
    const float* Wt = (g == 0) ? userW : itemW;
    const float* bt = (g == 0) ? userb : itemb;
    for (int i = threadIdx.x; i < 4096; i += blockDim.x) Wl[i] = Wt[i];
    if (threadIdx.x < 64) {
        btl[threadIdx.x] = bt[threadIdx.x];
        gl[threadIdx.x]  = ln_g[threadIdx.x];
        lbl[threadIdx.x] = ln_b[threadIdx.x];
    }
    if (threadIdx.x < 2) betal[threadIdx.x] = beta[((g == 0) ? 0 : 2) + threadIdx.x];
    __syncthreads();
    const float* z   = (g == 0) ? z_u : z_i;
    const int*  idx  = (g == 0) ? uidx : ((g == 1) ? iidx : nidx);
    const int lane = threadIdx.x & 63;
    const int wave = threadIdx.x >> 6;
    const int wpb  = blockDim.x >> 6;
    for (int r = blockIdx.x * wpb + wave; r < B; r += gridDim.x * wpb) {
        int node = idx[r];
        float e = betal[0] * z[(size_t)node * 64 + lane]
                + betal[1] * z[(size_t)(N + node) * 64 + lane];
        float y = btl[lane];
        #pragma unroll
        for (int k = 0; k < 64; ++k) y += __shfl(e, k) * Wl[k * 64 + lane];
        y = fmaxf(y, 0.f);
        float mu = wave_reduce_sum(y) * (1.f / 64.f);
        float d0 = y - mu;
        float var = wave_reduce_sum(d0 * d0) * (1.f / 64.f);
        float o = gl[lane] * d0 / sqrtf(var + 1e-5f) + lbl[lane];
        out[(size_t)(g * B + r) * 64 + lane] = o;
    }
}

extern "C" void kernel_launch(void* const* d_in, const int* in_sizes, int n_in,
                              void* d_out, int out_size, void* d_ws, size_t ws_size,
                              hipStream_t stream) {
    const int* user_idx = (const int*)d_in[0];
    const int* item_idx = (const int*)d_in[1];
    const int* neg_idx  = (const int*)d_in[2];
    const float* user_feat = (const float*)d_in[3];
    const float* item_feat = (const float*)d_in[4];
    const int* u_src = (const int*)d_in[5];
    const int* u_dst = (const int*)d_in[6];
    const int* i_src = (const int*)d_in[7];
    const int* i_dst = (const int*)d_in[8];
    const float* u_W  = (const float*)d_in[9];
    const float* u_al = (const float*)d_in[10];
    const float* u_ar = (const float*)d_in[11];
    const float* u_b  = (const float*)d_in[12];
    const float* i_W  = (const float*)d_in[13];
    const float* i_al = (const float*)d_in[14];
    const float* i_ar = (const float*)d_in[15];
    const float* i_b  = (const float*)d_in[16];
    const float* u_saW1 = (const float*)d_in[17];
    const float* u_sab1 = (const float*)d_in[18];
    const float* u_saW2 = (const float*)d_in[19];
    const float* i_saW1 = (const float*)d_in[20];
    const float* i_sab1 = (const float*)d_in[21];
    const float* i_saW2 = (const float*)d_in[22];
    const float* userW = (const float*)d_in[23];
    const float* userb = (const float*)d_in[24];
    const float* itemW = (const float*)d_in[25];
    const float* itemb = (const float*)d_in[26];
    const float* ln_g  = (const float*)d_in[27];
    const float* ln_b  = (const float*)d_in[28];

    const int N = N_NODES, E = N_EDGES, M = N_META, B = BATCH;

    char* ws = (char*)d_ws;
    size_t off = 0;
    auto alloc = [&](size_t bytes) -> char* {
        char* p = ws + off;
        off += (bytes + 255) & ~(size_t)255;
        return p;
    };
    float* z_u   = (float*)alloc((size_t)M * N * 64 * 4);
    float* z_i   = (float*)alloc((size_t)M * N * 64 * 4);
    float* feat  = (float*)alloc((size_t)M * N * 64 * 4);
    float* el    = (float*)alloc((size_t)M * N * 4);
    float* er    = (float*)alloc((size_t)M * N * 4);
    int* offsets = (int*)alloc((size_t)(N + 1) * 4);
    int* cursor  = (int*)alloc((size_t)N * 4);
    int* esrc    = (int*)alloc((size_t)E * 4);
    int* counts  = (int*)alloc((size_t)N * 4);
    float* wsum  = (float*)alloc(4 * 4);
    float* beta  = (float*)alloc(4 * 4);
    (void)ws_size; (void)in_sizes; (void)n_in; (void)out_size;

    dim3 blk(256);
    hipMemsetAsync(wsum, 0, 16, stream);

    for (int t = 0; t < 2; ++t) {
        const float* h    = t ? item_feat : user_feat;
        const float* W    = t ? i_W : u_W;
        const float* al   = t ? i_al : u_al;
        const float* ar   = t ? i_ar : u_ar;
        const float* bb   = t ? i_b : u_b;
        const int*   srcA = t ? i_src : u_src;
        const int*   dstA = t ? i_dst : u_dst;
        const float* saW1 = t ? i_saW1 : u_saW1;
        const float* sab1 = t ? i_sab1 : u_sab1;
        const float* saW2 = t ? i_saW2 : u_saW2;
        float* z = t ? z_i : z_u;

        feat_kernel<<<dim3(2048, N_META), blk, 0, stream>>>(h, W, al, ar, feat, el, er, N);
        for (int m = 0; m < M; ++m) {
            hipMemsetAsync(counts, 0, (size_t)N * 4, stream);
            hist_kernel<<<dim3(1024), blk, 0, stream>>>(dstA + (size_t)m * E, counts, E);
            scan_kernel<<<dim3(1), dim3(1024), 0, stream>>>(counts, offsets, N);
            copy_int<<<dim3(256), blk, 0, stream>>>(offsets, cursor, N);
            scatter_kernel<<<dim3(1024), blk, 0, stream>>>(srcA + (size_t)m * E, dstA + (size_t)m * E,
                                                           cursor, esrc, E);
            agg_kernel<<<dim3((N + 3) / 4), blk, 0, stream>>>(feat + (size_t)m * N * 64, el + m * N,
                                                              er + m * N, bb + m * 64, offsets, esrc,
                                                              z + (size_t)m * N * 64, N);
        }
        sem_kernel<<<dim3(1024, N_META), blk, 0, stream>>>(z, saW1, sab1, saW2, wsum + t * 2, N);
    }

    beta_kernel<<<1, 64, 0, stream>>>(wsum, beta, 1.f / (float)N);
    out_kernel<<<dim3((B + 3) / 4, 3), blk, 0, stream>>>(user_idx, item_idx, neg_idx, z_u, z_i, beta,
                                                         userW, userb, itemW, itemb, ln_g, ln_b,
                                                         (float*)d_out, N, B);
}

// Round 2
// 846.746 us; speedup vs baseline: 5.0433x; 5.0433x over previous
//
#include <hip/hip_runtime.h>
#include <math.h>

#define N_NODES 100000
#define N_EDGES 500000
#define BATCH   8192
#define NBLK    98   // ceil(N_NODES / 1024)

__device__ __forceinline__ float wave_reduce_sum(float v) {
    #pragma unroll
    for (int off = 32; off; off >>= 1) v += __shfl_xor(v, off);
    return v;
}

// feat[g] = h @ W[g]; el[g] = feat @ al[g]; er[g] = feat @ ar[g]
// g = t*2 + m  (t: 0=user 1=item). Lane l holds W[k][l] in VGPRs; h row read
// via wave-uniform scalar loads -> zero DS ops in the matmul.
__global__ void feat_all(const float* __restrict__ uf, const float* __restrict__ itf,
                         const float* __restrict__ uW, const float* __restrict__ iW,
                         const float* __restrict__ ual, const float* __restrict__ ial,
                         const float* __restrict__ uar, const float* __restrict__ iar,
                         float* __restrict__ feat, float* __restrict__ el,
                         float* __restrict__ er, int N) {
    const int g = blockIdx.y, t = g >> 1, m = g & 1;
    const float* h  = t ? itf : uf;
    const float* Wm = (t ? iW : uW) + (size_t)m * 4096;
    const float* alp = (t ? ial : ual) + m * 64;
    const float* arp = (t ? iar : uar) + m * 64;
    const int lane = threadIdx.x & 63, wave = threadIdx.x >> 6, wpb = blockDim.x >> 6;
    float Wc[64];
    #pragma unroll
    for (int k = 0; k < 64; ++k) Wc[k] = Wm[k * 64 + lane];
    const float alv = alp[lane], arv = arp[lane];
    float* fg  = feat + (size_t)g * N * 64;
    float* elg = el + (size_t)g * N;
    float* erg = er + (size_t)g * N;
    for (int row = blockIdx.x * wpb + wave; row < N; row += gridDim.x * wpb) {
        const int ur = __builtin_amdgcn_readfirstlane(row);
        const float* hr = h + (size_t)ur * 64;
        float f0 = 0.f, f1 = 0.f, f2 = 0.f, f3 = 0.f;
        #pragma unroll
        for (int k = 0; k < 64; k += 4) {
            f0 = fmaf(hr[k],     Wc[k],     f0);
            f1 = fmaf(hr[k + 1], Wc[k + 1], f1);
            f2 = fmaf(hr[k + 2], Wc[k + 2], f2);
            f3 = fmaf(hr[k + 3], Wc[k + 3], f3);
        }
        float f = (f0 + f1) + (f2 + f3);
        fg[(size_t)ur * 64 + lane] = f;
        float e1 = wave_reduce_sum(f * alv);
        float e2 = wave_reduce_sum(f * arv);
        if (lane == 0) { elg[ur] = e1; erg[ur] = e2; }
    }
}

__global__ void hist_all(const int* __restrict__ udst, const int* __restrict__ idst,
                         int* __restrict__ counts, int E, int N) {
    const int g = blockIdx.y;
    const int* dst = ((g < 2) ? udst : idst) + (size_t)(g & 1) * E;
    int* cnt = counts + (size_t)g * N;
    for (int i = blockIdx.x * blockDim.x + threadIdx.x; i < E; i += gridDim.x * blockDim.x)
        atomicAdd(&cnt[dst[i]], 1);
}

// per-1024-block exclusive scan + block totals
__global__ void scanA(const int* __restrict__ counts, int* __restrict__ offsets,
                      int* __restrict__ bsum, int N) {
    const int g = blockIdx.y;
    const int* c = counts + (size_t)g * N;
    int* o = offsets + (size_t)g * (N + 1);
    __shared__ int sh[1024];
    int i = blockIdx.x * 1024 + (int)threadIdx.x;
    int v = (i < N) ? c[i] : 0;
    sh[threadIdx.x] = v;
    __syncthreads();
    for (int off = 1; off < 1024; off <<= 1) {
        int tv = (threadIdx.x >= (unsigned)off) ? sh[threadIdx.x - off] : 0;
        __syncthreads();
        sh[threadIdx.x] += tv;
        __syncthreads();
    }
    if (i < N) o[i] = sh[threadIdx.x] - v;
    if (threadIdx.x == 1023) bsum[g * 128 + blockIdx.x] = sh[1023];
}

__global__ void scanB(int* __restrict__ bsum, int* __restrict__ offsets, int N) {
    const int g = blockIdx.y;
    int* bs = bsum + g * 128;
    __shared__ int sh[128];
    int tid = (int)threadIdx.x;
    int v = (tid < NBLK) ? bs[tid] : 0;
    sh[tid] = v;
    __syncthreads();
    for (int off = 1; off < 128; off <<= 1) {
        int tv = (tid >= off) ? sh[tid - off] : 0;
        __syncthreads();
        sh[tid] += tv;
        __syncthreads();
    }
    if (tid < NBLK) bs[tid] = sh[tid] - v;
    if (tid == 0) offsets[(size_t)g * (N + 1) + N] = sh[127];
}

__global__ void scanC(int* __restrict__ offsets, int* __restrict__ cursor,
                      const int* __restrict__ bsum, int N) {
    const int g = blockIdx.y;
    int i = blockIdx.x * blockDim.x + threadIdx.x;
    if (i < N) {
        int val = offsets[(size_t)g * (N + 1) + i] + bsum[g * 128 + (i >> 10)];
        offsets[(size_t)g * (N + 1) + i] = val;
        cursor[(size_t)g * N + i] = val;
    }
}

__global__ void scatter_all(const int* __restrict__ usrc, const int* __restrict__ udst,
                            const int* __restrict__ isrc, const int* __restrict__ idst,
                            int* __restrict__ cursor, int* __restrict__ esrc, int E, int N) {
    const int g = blockIdx.y;
    const int* src = ((g < 2) ? usrc : isrc) + (size_t)(g & 1) * E;
    const int* dst = ((g < 2) ? udst : idst) + (size_t)(g & 1) * E;
    int* cur = cursor + (size_t)g * N;
    int* es  = esrc + (size_t)g * E;
    for (int i = blockIdx.x * blockDim.x + threadIdx.x; i < E; i += gridDim.x * blockDim.x) {
        int pos = atomicAdd(&cur[dst[i]], 1);
        es[pos] = src[i];
    }
}

// wave-per-node, single-pass online edge-softmax + aggregate + elu(+b)
__global__ void agg_all(const float* __restrict__ feat, const float* __restrict__ el,
                        const float* __restrict__ er,
                        const float* __restrict__ ub, const float* __restrict__ ib,
                        const int* __restrict__ offsets, const int* __restrict__ esrc,
                        float* __restrict__ z, int E, int N) {
    const int g = blockIdx.y;
    const float* featg = feat + (size_t)g * N * 64;
    const float* elg = el + (size_t)g * N;
    const float* erg = er + (size_t)g * N;
    const float* bv = ((g < 2) ? ub : ib) + (g & 1) * 64;
    const int* offg = offsets + (size_t)g * (N + 1);
    const int* esg  = esrc + (size_t)g * E;
    float* zg = z + (size_t)g * N * 64;
    const int lane = threadIdx.x & 63, wave = threadIdx.x >> 6, wpb = blockDim.x >> 6;
    const float bl = bv[lane];
    for (int node = blockIdx.x * wpb + wave; node < N; node += gridDim.x * wpb) {
        const int un = __builtin_amdgcn_readfirstlane(node);
        int beg = offg[un], end = offg[un + 1];
        float erd = erg[un];
        float m = -INFINITY, l = 0.f, acc = 0.f;
        int sN = (beg < end) ? esg[beg] : 0;
        for (int i = beg; i < end; ++i) {
            int s = sN;
            sN = (i + 1 < end) ? esg[i + 1] : 0;
            float fv = featg[(size_t)s * 64 + lane];
            float e = elg[s] + erd;
            e = (e >= 0.f) ? e : 0.2f * e;
            if (e > m) {
                float sc = __expf(m - e);
                l = l * sc + 1.f;
                acc = acc * sc + fv;
                m = e;
            } else {
                float w = __expf(e - m);
                l += w;
                acc += w * fv;
            }
        }
        float o = acc / (l + 1e-9f);
        float zz = o + bl;
        zz = (zz > 0.f) ? zz : expm1f(zz);
        zg[(size_t)un * 64 + lane] = zz;
    }
}

// wsum[g] += sum_n tanh(z[g,n] @ W1 + b1) @ W2   (W1 in VGPRs, z via s_load)
__global__ void sem_all(const float* __restrict__ z,
                        const float* __restrict__ uW1, const float* __restrict__ iW1,
                        const float* __restrict__ ub1, const float* __restrict__ ib1,
                        const float* __restrict__ uW2, const float* __restrict__ iW2,
                        float* __restrict__ wsum, int N) {
    const int g = blockIdx.y, t = g >> 1;
    const float* W1 = t ? iW1 : uW1;
    const float* b1 = t ? ib1 : ub1;
    const float* W2 = t ? iW2 : uW2;
    const int lane = threadIdx.x & 63, wave = threadIdx.x >> 6, wpb = blockDim.x >> 6;
    float W1a[64], W1b[64];
    #pragma unroll
    for (int k = 0; k < 64; ++k) {
        W1a[k] = W1[k * 128 + lane];
        W1b[k] = W1[k * 128 + 64 + lane];
    }
    const float b1a = b1[lane], b1b = b1[64 + lane];
    const float w2a = W2[lane], w2b = W2[64 + lane];
    const float* zg = z + (size_t)g * N * 64;
    float local = 0.f;
    for (int row = blockIdx.x * wpb + wave; row < N; row += gridDim.x * wpb) {
        const int ur = __builtin_amdgcn_readfirstlane(row);
        const float* zr = zg + (size_t)ur * 64;
        float t0 = b1a, t0b = 0.f, t1 = b1b, t1b = 0.f;
        #pragma unroll
        for (int k = 0; k < 64; k += 2) {
            float za = zr[k], zb = zr[k + 1];
            t0  = fmaf(za, W1a[k],     t0);
            t0b = fmaf(zb, W1a[k + 1], t0b);
            t1  = fmaf(za, W1b[k],     t1);
            t1b = fmaf(zb, W1b[k + 1], t1b);
        }
        local += tanhf(t0 + t0b) * w2a + tanhf(t1 + t1b) * w2b;
    }
    local = wave_reduce_sum(local);
    if (lane == 0) atomicAdd(&wsum[g], local);
}

// gather + beta-combine + proj + relu + layernorm for the indexed rows only
__global__ void out_all(const int* __restrict__ uidx, const int* __restrict__ iidx,
                        const int* __restrict__ nidx, const float* __restrict__ z,
                        const float* __restrict__ wsum,
                        const float* __restrict__ userW, const float* __restrict__ userb,
                        const float* __restrict__ itemW, const float* __restrict__ itemb,
                        const float* __restrict__ ln_g, const float* __restrict__ ln_b,
                        float* __restrict__ out, int N, int B) {
    const int grp = blockIdx.y;
    const int t = (grp == 0) ? 0 : 1;
    const float* Wt = t ? itemW : userW;
    const float* bt = t ? itemb : userb;
    const int* idx = (grp == 0) ? uidx : ((grp == 1) ? iidx : nidx);
    const float* zg = z + (size_t)(t * 2) * N * 64;
    const int lane = threadIdx.x & 63, wave = threadIdx.x >> 6, wpb = blockDim.x >> 6;
    float Wc[64];
    #pragma unroll
    for (int k = 0; k < 64; ++k) Wc[k] = Wt[k * 64 + lane];
    const float btl = bt[lane], gl = ln_g[lane], lbl = ln_b[lane];
    const float invN = 1.f / (float)N;
    float w0 = wsum[t * 2] * invN, w1 = wsum[t * 2 + 1] * invN;
    float mx = fmaxf(w0, w1);
    float e0 = __expf(w0 - mx), e1 = __expf(w1 - mx);
    float bsum = e0 + e1;
    float beta0 = e0 / bsum, beta1 = e1 / bsum;
    for (int r = blockIdx.x * wpb + wave; r < B; r += gridDim.x * wpb) {
        const int urr = __builtin_amdgcn_readfirstlane(r);
        const int un = __builtin_amdgcn_readfirstlane(idx[urr]);
        float e = beta0 * zg[(size_t)un * 64 + lane] + beta1 * zg[(size_t)(N + un) * 64 + lane];
        float y = btl;
        #pragma unroll
        for (int k = 0; k < 64; ++k) y = fmaf(__shfl(e, k), Wc[k], y);
        y = fmaxf(y, 0.f);
        float mu = wave_reduce_sum(y) * (1.f / 64.f);
        float d = y - mu;
        float var = wave_reduce_sum(d * d) * (1.f / 64.f);
        out[(size_t)(grp * B + r) * 64 + lane] = gl * d / sqrtf(var + 1e-5f) + lbl;
    }
}

extern "C" void kernel_launch(void* const* d_in, const int* in_sizes, int n_in,
                              void* d_out, int out_size, void* d_ws, size_t ws_size,
                              hipStream_t stream) {
    const int* user_idx = (const int*)d_in[0];
    const int* item_idx = (const int*)d_in[1];
    const int* neg_idx  = (const int*)d_in[2];
    const float* user_feat = (const float*)d_in[3];
    const float* item_feat = (const float*)d_in[4];
    const int* u_src = (const int*)d_in[5];
    const int* u_dst = (const int*)d_in[6];
    const int* i_src = (const int*)d_in[7];
    const int* i_dst = (const int*)d_in[8];
    const float* u_W  = (const float*)d_in[9];
    const float* u_al = (const float*)d_in[10];
    const float* u_ar = (const float*)d_in[11];
    const float* u_b  = (const float*)d_in[12];
    const float* i_W  = (const float*)d_in[13];
    const float* i_al = (const float*)d_in[14];
    const float* i_ar = (const float*)d_in[15];
    const float* i_b  = (const float*)d_in[16];
    const float* u_saW1 = (const float*)d_in[17];
    const float* u_sab1 = (const float*)d_in[18];
    const float* u_saW2 = (const float*)d_in[19];
    const float* i_saW1 = (const float*)d_in[20];
    const float* i_sab1 = (const float*)d_in[21];
    const float* i_saW2 = (const float*)d_in[22];
    const float* userW = (const float*)d_in[23];
    const float* userb = (const float*)d_in[24];
    const float* itemW = (const float*)d_in[25];
    const float* itemb = (const float*)d_in[26];
    const float* ln_g  = (const float*)d_in[27];
    const float* ln_b  = (const float*)d_in[28];

    const int N = N_NODES, E = N_EDGES, B = BATCH;

    char* ws = (char*)d_ws;
    size_t off = 0;
    auto alloc = [&](size_t bytes) -> char* {
        char* p = ws + off;
        off += (bytes + 255) & ~(size_t)255;
        return p;
    };
    float* feat  = (float*)alloc((size_t)4 * N * 64 * 4);   // 102.4 MB
    float* z     = (float*)alloc((size_t)4 * N * 64 * 4);   // 102.4 MB
    float* el    = (float*)alloc((size_t)4 * N * 4);
    float* er    = (float*)alloc((size_t)4 * N * 4);
    int* offsets = (int*)alloc((size_t)4 * (N + 1) * 4);
    int* cursor  = (int*)alloc((size_t)4 * N * 4);
    int* counts  = (int*)alloc((size_t)4 * N * 4);
    int* esrc    = (int*)alloc((size_t)4 * E * 4);
    int* bsum    = (int*)alloc((size_t)4 * 128 * 4);
    float* wsum  = (float*)alloc(16);
    (void)ws_size; (void)in_sizes; (void)n_in; (void)out_size;

    dim3 blk(256);
    hipMemsetAsync(wsum, 0, 16, stream);
    hipMemsetAsync(counts, 0, (size_t)4 * N * 4, stream);

    feat_all<<<dim3(512, 4), blk, 0, stream>>>(user_feat, item_feat, u_W, i_W,
                                               u_al, i_al, u_ar, i_ar, feat, el, er, N);
    hist_all<<<dim3(512, 4), blk, 0, stream>>>(u_dst, i_dst, counts, E, N);
    scanA<<<dim3(NBLK, 4), dim3(1024), 0, stream>>>(counts, offsets, bsum, N);
    scanB<<<dim3(1, 4), dim3(128), 0, stream>>>(bsum, offsets, N);
    scanC<<<dim3(391, 4), blk, 0, stream>>>(offsets, cursor, bsum, N);
    scatter_all<<<dim3(512, 4), blk, 0, stream>>>(u_src, u_dst, i_src, i_dst,
                                                  cursor, esrc, E, N);
    agg_all<<<dim3(4096, 4), blk, 0, stream>>>(feat, el, er, u_b, i_b,
                                               offsets, esrc, z, E, N);
    sem_all<<<dim3(256, 4), blk, 0, stream>>>(z, u_saW1, i_saW1, u_sab1, i_sab1,
                                              u_saW2, i_saW2, wsum, N);
    out_all<<<dim3(512, 3), blk, 0, stream>>>(user_idx, item_idx, neg_idx, z, wsum,
                                              userW, userb, itemW, itemb, ln_g, ln_b,
                                              (float*)d_out, N, B);
}

// Round 4
// 549.944 us; speedup vs baseline: 7.7652x; 1.5397x over previous
//
#include <hip/hip_runtime.h>
#include <math.h>

#define N_NODES 100000
#define N_EDGES 500000
#define BATCH   8192
#define NBLK    98   // ceil(N_NODES / 1024)

typedef __bf16 bf16x8 __attribute__((ext_vector_type(8)));
typedef float  f32x4  __attribute__((ext_vector_type(4)));

#define MFMA16(a, b, c) __builtin_amdgcn_mfma_f32_16x16x32_bf16((a), (b), (c), 0, 0, 0)

__device__ __forceinline__ float wave_reduce_sum(float v) {
    #pragma unroll
    for (int off = 32; off; off >>= 1) v += __shfl_xor(v, off);
    return v;
}

__device__ __forceinline__ float fast_tanh(float x) {
    float e = __expf(2.f * x);
    return 1.f - 2.f / (e + 1.f);
}

// feat[g] = h @ W[g] (MFMA bf16). el/er = feat @ al / feat @ ar computed from
// the accumulators via a 16-lane butterfly (NOT from h -- that was R3's bug).
// A-frag: row=lane&15, k=(lane>>4)*8+j (contiguous 8, verified m97 layout);
// C/D: col=lane&15, row=(lane>>4)*4+reg.
__global__ void feat_mfma(const float* __restrict__ uf, const float* __restrict__ itf,
                          const float* __restrict__ uW, const float* __restrict__ iW,
                          const float* __restrict__ ual, const float* __restrict__ ial,
                          const float* __restrict__ uar, const float* __restrict__ iar,
                          float* __restrict__ feat, float* __restrict__ el,
                          float* __restrict__ er, int N) {
    const int t = blockIdx.y;
    const float* h   = t ? itf : uf;
    const float* Wb  = t ? iW : uW;
    const float* alb = t ? ial : ual;
    const float* arb = t ? iar : uar;
    const int lane = threadIdx.x & 63, wave = threadIdx.x >> 6, wpb = blockDim.x >> 6;
    const int c = lane & 15, q = lane >> 4;
    bf16x8 bW[2][4][2];
    float alv[2][4], arv[2][4];
    #pragma unroll
    for (int m = 0; m < 2; ++m) {
        const float* Wm = Wb + m * 4096;
        #pragma unroll
        for (int nt = 0; nt < 4; ++nt) {
            #pragma unroll
            for (int kf = 0; kf < 2; ++kf)
                #pragma unroll
                for (int j = 0; j < 8; ++j)
                    bW[m][nt][kf][j] = (__bf16)Wm[(kf * 32 + q * 8 + j) * 64 + nt * 16 + c];
            alv[m][nt] = alb[m * 64 + nt * 16 + c];
            arv[m][nt] = arb[m * 64 + nt * 16 + c];
        }
    }
    const f32x4 zf = {0.f, 0.f, 0.f, 0.f};
    const int tiles = N >> 4;
    for (int tile = blockIdx.x * wpb + wave; tile < tiles; tile += gridDim.x * wpb) {
        const float* hr = h + (size_t)(tile * 16 + c) * 64 + q * 8;
        f32x4 v0 = *(const f32x4*)hr;
        f32x4 v1 = *(const f32x4*)(hr + 4);
        f32x4 v2 = *(const f32x4*)(hr + 32);
        f32x4 v3 = *(const f32x4*)(hr + 36);
        bf16x8 a0, a1;
        #pragma unroll
        for (int j = 0; j < 4; ++j) {
            a0[j] = (__bf16)v0[j]; a0[j + 4] = (__bf16)v1[j];
            a1[j] = (__bf16)v2[j]; a1[j + 4] = (__bf16)v3[j];
        }
        #pragma unroll
        for (int m = 0; m < 2; ++m) {
            const int g = t * 2 + m;
            float* fg  = feat + (size_t)g * N * 64;
            float* elg = el + (size_t)g * N;
            float* erg = er + (size_t)g * N;
            f32x4 acc[4];
            #pragma unroll
            for (int nt = 0; nt < 4; ++nt) {
                acc[nt] = zf;
                acc[nt] = MFMA16(a0, bW[m][nt][0], acc[nt]);
                acc[nt] = MFMA16(a1, bW[m][nt][1], acc[nt]);
            }
            #pragma unroll
            for (int nt = 0; nt < 4; ++nt)
                #pragma unroll
                for (int r = 0; r < 4; ++r)
                    fg[(size_t)(tile * 16 + q * 4 + r) * 64 + nt * 16 + c] = acc[nt][r];
            // el/er from feat accumulators: reduce over columns
            #pragma unroll
            for (int r = 0; r < 4; ++r) {
                float se = 0.f, sr = 0.f;
                #pragma unroll
                for (int nt = 0; nt < 4; ++nt) {
                    se = fmaf(acc[nt][r], alv[m][nt], se);
                    sr = fmaf(acc[nt][r], arv[m][nt], sr);
                }
                #pragma unroll
                for (int off = 1; off < 16; off <<= 1) {
                    se += __shfl_xor(se, off);
                    sr += __shfl_xor(sr, off);
                }
                if (c == 0) {
                    elg[tile * 16 + q * 4 + r] = se;
                    erg[tile * 16 + q * 4 + r] = sr;
                }
            }
        }
    }
}

__global__ void hist_all(const int* __restrict__ udst, const int* __restrict__ idst,
                         int* __restrict__ counts, int E, int N) {
    const int g = blockIdx.y;
    const int* dst = ((g < 2) ? udst : idst) + (size_t)(g & 1) * E;
    int* cnt = counts + (size_t)g * N;
    for (int i = blockIdx.x * blockDim.x + threadIdx.x; i < E; i += gridDim.x * blockDim.x)
        atomicAdd(&cnt[dst[i]], 1);
}

__global__ void scanA(const int* __restrict__ counts, int* __restrict__ offsets,
                      int* __restrict__ bsum, int N) {
    const int g = blockIdx.y;
    const int* c = counts + (size_t)g * N;
    int* o = offsets + (size_t)g * (N + 1);
    __shared__ int sh[1024];
    int i = blockIdx.x * 1024 + (int)threadIdx.x;
    int v = (i < N) ? c[i] : 0;
    sh[threadIdx.x] = v;
    __syncthreads();
    for (int off = 1; off < 1024; off <<= 1) {
        int tv = (threadIdx.x >= (unsigned)off) ? sh[threadIdx.x - off] : 0;
        __syncthreads();
        sh[threadIdx.x] += tv;
        __syncthreads();
    }
    if (i < N) o[i] = sh[threadIdx.x] - v;
    if (threadIdx.x == 1023) bsum[g * 128 + blockIdx.x] = sh[1023];
}

__global__ void scanB(int* __restrict__ bsum, int* __restrict__ offsets, int N) {
    const int g = blockIdx.y;
    int* bs = bsum + g * 128;
    __shared__ int sh[128];
    int tid = (int)threadIdx.x;
    int v = (tid < NBLK) ? bs[tid] : 0;
    sh[tid] = v;
    __syncthreads();
    for (int off = 1; off < 128; off <<= 1) {
        int tv = (tid >= off) ? sh[tid - off] : 0;
        __syncthreads();
        sh[tid] += tv;
        __syncthreads();
    }
    if (tid < NBLK) bs[tid] = sh[tid] - v;
    if (tid == 0) offsets[(size_t)g * (N + 1) + N] = sh[127];
}

__global__ void scanC(int* __restrict__ offsets, int* __restrict__ cursor,
                      const int* __restrict__ bsum, int N) {
    const int g = blockIdx.y;
    int i = blockIdx.x * blockDim.x + threadIdx.x;
    if (i < N) {
        int val = offsets[(size_t)g * (N + 1) + i] + bsum[g * 128 + (i >> 10)];
        offsets[(size_t)g * (N + 1) + i] = val;
        cursor[(size_t)g * N + i] = val;
    }
}

// CSR scatter + per-edge softmax weight w = exp(leakyrelu(el[s]+er[d]))
// (softmax ratio is shift-invariant; |e| <= ~7 so exp is safe in f32)
__global__ void scatter_all(const int* __restrict__ usrc, const int* __restrict__ udst,
                            const int* __restrict__ isrc, const int* __restrict__ idst,
                            const float* __restrict__ el, const float* __restrict__ er,
                            int* __restrict__ cursor, int2* __restrict__ epack, int E, int N) {
    const int g = blockIdx.y;
    const int* src = ((g < 2) ? usrc : isrc) + (size_t)(g & 1) * E;
    const int* dst = ((g < 2) ? udst : idst) + (size_t)(g & 1) * E;
    const float* elg = el + (size_t)g * N;
    const float* erg = er + (size_t)g * N;
    int* cur = cursor + (size_t)g * N;
    int2* ep = epack + (size_t)g * E;
    for (int i = blockIdx.x * blockDim.x + threadIdx.x; i < E; i += gridDim.x * blockDim.x) {
        int s = src[i], d = dst[i];
        int pos = atomicAdd(&cur[d], 1);
        float e = elg[s] + erg[d];
        e = (e >= 0.f) ? e : 0.2f * e;
        float w = __expf(e);
        ep[pos] = make_int2(s, __float_as_int(w));
    }
}

// wave-per-node: den + weighted aggregate + elu(+b)
__global__ void agg_all(const float* __restrict__ feat,
                        const float* __restrict__ ub, const float* __restrict__ ib,
                        const int* __restrict__ offsets, const int2* __restrict__ epack,
                        float* __restrict__ z, int E, int N) {
    const int g = blockIdx.y;
    const float* featg = feat + (size_t)g * N * 64;
    const float* bv = ((g < 2) ? ub : ib) + (g & 1) * 64;
    const int* offg = offsets + (size_t)g * (N + 1);
    const int2* ep = epack + (size_t)g * E;
    float* zg = z + (size_t)g * N * 64;
    const int lane = threadIdx.x & 63, wave = threadIdx.x >> 6, wpb = blockDim.x >> 6;
    const float bl = bv[lane];
    for (int node = blockIdx.x * wpb + wave; node < N; node += gridDim.x * wpb) {
        int beg = offg[node], end = offg[node + 1];
        float l = 0.f, acc = 0.f;
        for (int i = beg; i < end; ++i) {
            int2 p = ep[i];
            float w = __int_as_float(p.y);
            l += w;
            acc = fmaf(w, featg[(size_t)p.x * 64 + lane], acc);
        }
        float o = acc / (l + 1e-9f);
        float zz = o + bl;
        zz = (zz > 0.f) ? zz : expm1f(zz);
        zg[(size_t)node * 64 + lane] = zz;
    }
}

// wsum[g] += sum_n tanh(z[g,n] @ W1 + b1) @ W2  -- MFMA over 16-row tiles
__global__ void sem_mfma(const float* __restrict__ z,
                         const float* __restrict__ uW1, const float* __restrict__ iW1,
                         const float* __restrict__ ub1, const float* __restrict__ ib1,
                         const float* __restrict__ uW2, const float* __restrict__ iW2,
                         float* __restrict__ wsum, int N) {
    const int g = blockIdx.y, t = g >> 1;
    const float* W1 = t ? iW1 : uW1;
    const float* b1 = t ? ib1 : ub1;
    const float* W2 = t ? iW2 : uW2;
    const int lane = threadIdx.x & 63, wave = threadIdx.x >> 6, wpb = blockDim.x >> 6;
    const int c = lane & 15, q = lane >> 4;
    bf16x8 bfr[8][2];
    #pragma unroll
    for (int nt = 0; nt < 8; ++nt)
        #pragma unroll
        for (int kf = 0; kf < 2; ++kf)
            #pragma unroll
            for (int j = 0; j < 8; ++j)
                bfr[nt][kf][j] = (__bf16)W1[(kf * 32 + q * 8 + j) * 128 + nt * 16 + c];
    float b1v[8], w2v[8];
    #pragma unroll
    for (int nt = 0; nt < 8; ++nt) { b1v[nt] = b1[nt * 16 + c]; w2v[nt] = W2[nt * 16 + c]; }
    const float* zg = z + (size_t)g * N * 64;
    const f32x4 zf = {0.f, 0.f, 0.f, 0.f};
    float local = 0.f;
    const int tiles = N >> 4;
    for (int tile = blockIdx.x * wpb + wave; tile < tiles; tile += gridDim.x * wpb) {
        const float* zr = zg + (size_t)(tile * 16 + c) * 64 + q * 8;
        f32x4 v0 = *(const f32x4*)zr;
        f32x4 v1 = *(const f32x4*)(zr + 4);
        f32x4 v2 = *(const f32x4*)(zr + 32);
        f32x4 v3 = *(const f32x4*)(zr + 36);
        bf16x8 a0, a1;
        #pragma unroll
        for (int j = 0; j < 4; ++j) {
            a0[j] = (__bf16)v0[j]; a0[j + 4] = (__bf16)v1[j];
            a1[j] = (__bf16)v2[j]; a1[j + 4] = (__bf16)v3[j];
        }
        f32x4 acc[8];
        #pragma unroll
        for (int nt = 0; nt < 8; ++nt) {
            acc[nt] = zf;
            acc[nt] = MFMA16(a0, bfr[nt][0], acc[nt]);
            acc[nt] = MFMA16(a1, bfr[nt][1], acc[nt]);
        }
        #pragma unroll
        for (int nt = 0; nt < 8; ++nt)
            #pragma unroll
            for (int r = 0; r < 4; ++r)
                local += w2v[nt] * fast_tanh(acc[nt][r] + b1v[nt]);
    }
    local = wave_reduce_sum(local);
    if (lane == 0) atomicAdd(&wsum[g], local);
}

// gather + beta-combine + proj + relu + layernorm for indexed rows
__global__ void out_all(const int* __restrict__ uidx, const int* __restrict__ iidx,
                        const int* __restrict__ nidx, const float* __restrict__ z,
                        const float* __restrict__ wsum,
                        const float* __restrict__ userW, const float* __restrict__ userb,
                        const float* __restrict__ itemW, const float* __restrict__ itemb,
                        const float* __restrict__ ln_g, const float* __restrict__ ln_b,
                        float* __restrict__ out, int N, int B) {
    const int grp = blockIdx.y;
    const int t = (grp == 0) ? 0 : 1;
    const float* Wt = t ? itemW : userW;
    const float* bt = t ? itemb : userb;
    const int* idx = (grp == 0) ? uidx : ((grp == 1) ? iidx : nidx);
    const float* zg = z + (size_t)(t * 2) * N * 64;
    const int lane = threadIdx.x & 63, wave = threadIdx.x >> 6, wpb = blockDim.x >> 6;
    float Wc[64];
    #pragma unroll
    for (int k = 0; k < 64; ++k) Wc[k] = Wt[k * 64 + lane];
    const float btl = bt[lane], gl = ln_g[lane], lbl = ln_b[lane];
    const float invN = 1.f / (float)N;
    float w0 = wsum[t * 2] * invN, w1 = wsum[t * 2 + 1] * invN;
    float mx = fmaxf(w0, w1);
    float e0 = __expf(w0 - mx), e1 = __expf(w1 - mx);
    float bsum = e0 + e1;
    float beta0 = e0 / bsum, beta1 = e1 / bsum;
    for (int r = blockIdx.x * wpb + wave; r < B; r += gridDim.x * wpb) {
        const int urr = __builtin_amdgcn_readfirstlane(r);
        const int un = __builtin_amdgcn_readfirstlane(idx[urr]);
        float e = beta0 * zg[(size_t)un * 64 + lane] + beta1 * zg[(size_t)(N + un) * 64 + lane];
        float y = btl;
        #pragma unroll
        for (int k = 0; k < 64; ++k) y = fmaf(__shfl(e, k), Wc[k], y);
        y = fmaxf(y, 0.f);
        float mu = wave_reduce_sum(y) * (1.f / 64.f);
        float d = y - mu;
        float var = wave_reduce_sum(d * d) * (1.f / 64.f);
        out[(size_t)(grp * B + r) * 64 + lane] = gl * d / sqrtf(var + 1e-5f) + lbl;
    }
}

extern "C" void kernel_launch(void* const* d_in, const int* in_sizes, int n_in,
                              void* d_out, int out_size, void* d_ws, size_t ws_size,
                              hipStream_t stream) {
    const int* user_idx = (const int*)d_in[0];
    const int* item_idx = (const int*)d_in[1];
    const int* neg_idx  = (const int*)d_in[2];
    const float* user_feat = (const float*)d_in[3];
    const float* item_feat = (const float*)d_in[4];
    const int* u_src = (const int*)d_in[5];
    const int* u_dst = (const int*)d_in[6];
    const int* i_src = (const int*)d_in[7];
    const int* i_dst = (const int*)d_in[8];
    const float* u_W  = (const float*)d_in[9];
    const float* u_al = (const float*)d_in[10];
    const float* u_ar = (const float*)d_in[11];
    const float* u_b  = (const float*)d_in[12];
    const float* i_W  = (const float*)d_in[13];
    const float* i_al = (const float*)d_in[14];
    const float* i_ar = (const float*)d_in[15];
    const float* i_b  = (const float*)d_in[16];
    const float* u_saW1 = (const float*)d_in[17];
    const float* u_sab1 = (const float*)d_in[18];
    const float* u_saW2 = (const float*)d_in[19];
    const float* i_saW1 = (const float*)d_in[20];
    const float* i_sab1 = (const float*)d_in[21];
    const float* i_saW2 = (const float*)d_in[22];
    const float* userW = (const float*)d_in[23];
    const float* userb = (const float*)d_in[24];
    const float* itemW = (const float*)d_in[25];
    const float* itemb = (const float*)d_in[26];
    const float* ln_g  = (const float*)d_in[27];
    const float* ln_b  = (const float*)d_in[28];

    const int N = N_NODES, E = N_EDGES, B = BATCH;

    char* ws = (char*)d_ws;
    size_t off = 0;
    auto alloc = [&](size_t bytes) -> char* {
        char* p = ws + off;
        off += (bytes + 255) & ~(size_t)255;
        return p;
    };
    float* feat  = (float*)alloc((size_t)4 * N * 64 * 4);   // 102.4 MB
    float* z     = (float*)alloc((size_t)4 * N * 64 * 4);   // 102.4 MB
    float* el    = (float*)alloc((size_t)4 * N * 4);
    float* er    = (float*)alloc((size_t)4 * N * 4);
    int* offsets = (int*)alloc((size_t)4 * (N + 1) * 4);
    int* cursor  = (int*)alloc((size_t)4 * N * 4);
    int* counts  = (int*)alloc((size_t)4 * N * 4);
    int2* epack  = (int2*)alloc((size_t)4 * E * 8);         // 16 MB
    int* bsum    = (int*)alloc((size_t)4 * 128 * 4);
    float* wsum  = (float*)alloc(16);
    (void)ws_size; (void)in_sizes; (void)n_in; (void)out_size;

    dim3 blk(256);
    hipMemsetAsync(wsum, 0, 16, stream);
    hipMemsetAsync(counts, 0, (size_t)4 * N * 4, stream);

    feat_mfma<<<dim3(256, 2), blk, 0, stream>>>(user_feat, item_feat, u_W, i_W,
                                                u_al, i_al, u_ar, i_ar, feat, el, er, N);
    hist_all<<<dim3(512, 4), blk, 0, stream>>>(u_dst, i_dst, counts, E, N);
    scanA<<<dim3(NBLK, 4), dim3(1024), 0, stream>>>(counts, offsets, bsum, N);
    scanB<<<dim3(1, 4), dim3(128), 0, stream>>>(bsum, offsets, N);
    scanC<<<dim3(391, 4), blk, 0, stream>>>(offsets, cursor, bsum, N);
    scatter_all<<<dim3(512, 4), blk, 0, stream>>>(u_src, u_dst, i_src, i_dst,
                                                  el, er, cursor, epack, E, N);
    agg_all<<<dim3(2048, 4), blk, 0, stream>>>(feat, u_b, i_b, offsets, epack, z, E, N);
    sem_mfma<<<dim3(256, 4), blk, 0, stream>>>(z, u_saW1, i_saW1, u_sab1, i_sab1,
                                               u_saW2, i_saW2, wsum, N);
    out_all<<<dim3(512, 3), blk, 0, stream>>>(user_idx, item_idx, neg_idx, z, wsum,
                                              userW, userb, itemW, itemb, ln_g, ln_b,
                                              (float*)d_out, N, B);
}

// Round 5
// 432.330 us; speedup vs baseline: 9.8777x; 1.2720x over previous
//
#include <hip/hip_runtime.h>
#include <math.h>

#define N_NODES 100000
#define N_EDGES 500000
#define BATCH   8192
#define NBLK    98   // ceil(N_NODES / 1024)

typedef __bf16 bf16;
typedef __bf16 bf16x8 __attribute__((ext_vector_type(8)));
typedef float  f32x4  __attribute__((ext_vector_type(4)));

#define MFMA16(a, b, c) __builtin_amdgcn_mfma_f32_16x16x32_bf16((a), (b), (c), 0, 0, 0)

__device__ __forceinline__ float wave_reduce_sum(float v) {
    #pragma unroll
    for (int off = 32; off; off >>= 1) v += __shfl_xor(v, off);
    return v;
}

__device__ __forceinline__ float fast_tanh(float x) {
    float e = __expf(2.f * x);
    return 1.f - 2.f / (e + 1.f);
}

__device__ __forceinline__ float b2f(unsigned short u) {
    return __int_as_float(((int)u) << 16);
}

// feat[g] = h @ W[g] (MFMA bf16), stored as bf16. el/er = feat@al / feat@ar
// from the accumulators via 16-lane butterfly (kept f32).
// A-frag: row=lane&15, k=(lane>>4)*8+j ; C/D: col=lane&15, row=(lane>>4)*4+reg.
__global__ void feat_mfma(const float* __restrict__ uf, const float* __restrict__ itf,
                          const float* __restrict__ uW, const float* __restrict__ iW,
                          const float* __restrict__ ual, const float* __restrict__ ial,
                          const float* __restrict__ uar, const float* __restrict__ iar,
                          bf16* __restrict__ feat, float* __restrict__ el,
                          float* __restrict__ er, int N) {
    const int t = blockIdx.y;
    const float* h   = t ? itf : uf;
    const float* Wb  = t ? iW : uW;
    const float* alb = t ? ial : ual;
    const float* arb = t ? iar : uar;
    const int lane = threadIdx.x & 63, wave = threadIdx.x >> 6, wpb = blockDim.x >> 6;
    const int c = lane & 15, q = lane >> 4;
    bf16x8 bW[2][4][2];
    float alv[2][4], arv[2][4];
    #pragma unroll
    for (int m = 0; m < 2; ++m) {
        const float* Wm = Wb + m * 4096;
        #pragma unroll
        for (int nt = 0; nt < 4; ++nt) {
            #pragma unroll
            for (int kf = 0; kf < 2; ++kf)
                #pragma unroll
                for (int j = 0; j < 8; ++j)
                    bW[m][nt][kf][j] = (bf16)Wm[(kf * 32 + q * 8 + j) * 64 + nt * 16 + c];
            alv[m][nt] = alb[m * 64 + nt * 16 + c];
            arv[m][nt] = arb[m * 64 + nt * 16 + c];
        }
    }
    const f32x4 zf = {0.f, 0.f, 0.f, 0.f};
    const int tiles = N >> 4;
    for (int tile = blockIdx.x * wpb + wave; tile < tiles; tile += gridDim.x * wpb) {
        const float* hr = h + (size_t)(tile * 16 + c) * 64 + q * 8;
        f32x4 v0 = *(const f32x4*)hr;
        f32x4 v1 = *(const f32x4*)(hr + 4);
        f32x4 v2 = *(const f32x4*)(hr + 32);
        f32x4 v3 = *(const f32x4*)(hr + 36);
        bf16x8 a0, a1;
        #pragma unroll
        for (int j = 0; j < 4; ++j) {
            a0[j] = (bf16)v0[j]; a0[j + 4] = (bf16)v1[j];
            a1[j] = (bf16)v2[j]; a1[j + 4] = (bf16)v3[j];
        }
        #pragma unroll
        for (int m = 0; m < 2; ++m) {
            const int g = t * 2 + m;
            bf16* fg   = feat + (size_t)g * N * 64;
            float* elg = el + (size_t)g * N;
            float* erg = er + (size_t)g * N;
            f32x4 acc[4];
            #pragma unroll
            for (int nt = 0; nt < 4; ++nt) {
                acc[nt] = zf;
                acc[nt] = MFMA16(a0, bW[m][nt][0], acc[nt]);
                acc[nt] = MFMA16(a1, bW[m][nt][1], acc[nt]);
            }
            #pragma unroll
            for (int nt = 0; nt < 4; ++nt)
                #pragma unroll
                for (int r = 0; r < 4; ++r)
                    fg[(size_t)(tile * 16 + q * 4 + r) * 64 + nt * 16 + c] = (bf16)acc[nt][r];
            #pragma unroll
            for (int r = 0; r < 4; ++r) {
                float se = 0.f, sr = 0.f;
                #pragma unroll
                for (int nt = 0; nt < 4; ++nt) {
                    se = fmaf(acc[nt][r], alv[m][nt], se);
                    sr = fmaf(acc[nt][r], arv[m][nt], sr);
                }
                #pragma unroll
                for (int off = 1; off < 16; off <<= 1) {
                    se += __shfl_xor(se, off);
                    sr += __shfl_xor(sr, off);
                }
                if (c == 0) {
                    elg[tile * 16 + q * 4 + r] = se;
                    erg[tile * 16 + q * 4 + r] = sr;
                }
            }
        }
    }
}

__global__ void hist_all(const int* __restrict__ udst, const int* __restrict__ idst,
                         int* __restrict__ counts, int E, int N) {
    const int g = blockIdx.y;
    const int* dst = ((g < 2) ? udst : idst) + (size_t)(g & 1) * E;
    int* cnt = counts + (size_t)g * N;
    for (int i = blockIdx.x * blockDim.x + threadIdx.x; i < E; i += gridDim.x * blockDim.x)
        atomicAdd(&cnt[dst[i]], 1);
}

__global__ void scanA(const int* __restrict__ counts, int* __restrict__ offsets,
                      int* __restrict__ bsum, int N) {
    const int g = blockIdx.y;
    const int* c = counts + (size_t)g * N;
    int* o = offsets + (size_t)g * (N + 1);
    __shared__ int sh[1024];
    int i = blockIdx.x * 1024 + (int)threadIdx.x;
    int v = (i < N) ? c[i] : 0;
    sh[threadIdx.x] = v;
    __syncthreads();
    for (int off = 1; off < 1024; off <<= 1) {
        int tv = (threadIdx.x >= (unsigned)off) ? sh[threadIdx.x - off] : 0;
        __syncthreads();
        sh[threadIdx.x] += tv;
        __syncthreads();
    }
    if (i < N) o[i] = sh[threadIdx.x] - v;
    if (threadIdx.x == 1023) bsum[g * 128 + blockIdx.x] = sh[1023];
}

__global__ void scanB(int* __restrict__ bsum, int* __restrict__ offsets, int N) {
    const int g = blockIdx.y;
    int* bs = bsum + g * 128;
    __shared__ int sh[128];
    int tid = (int)threadIdx.x;
    int v = (tid < NBLK) ? bs[tid] : 0;
    sh[tid] = v;
    __syncthreads();
    for (int off = 1; off < 128; off <<= 1) {
        int tv = (tid >= off) ? sh[tid - off] : 0;
        __syncthreads();
        sh[tid] += tv;
        __syncthreads();
    }
    if (tid < NBLK) bs[tid] = sh[tid] - v;
    if (tid == 0) offsets[(size_t)g * (N + 1) + N] = sh[127];
}

__global__ void scanC(int* __restrict__ offsets, int* __restrict__ cursor,
                      const int* __restrict__ bsum, int N) {
    const int g = blockIdx.y;
    int i = blockIdx.x * blockDim.x + threadIdx.x;
    if (i < N) {
        int val = offsets[(size_t)g * (N + 1) + i] + bsum[g * 128 + (i >> 10)];
        offsets[(size_t)g * (N + 1) + i] = val;
        cursor[(size_t)g * N + i] = val;
    }
}

// CSR scatter + per-edge softmax weight w = exp(leakyrelu(el[s]+er[d]))
// (softmax ratio is shift-invariant; |e| small so exp is safe in f32)
__global__ void scatter_all(const int* __restrict__ usrc, const int* __restrict__ udst,
                            const int* __restrict__ isrc, const int* __restrict__ idst,
                            const float* __restrict__ el, const float* __restrict__ er,
                            int* __restrict__ cursor, int2* __restrict__ epack, int E, int N) {
    const int g = blockIdx.y;
    const int* src = ((g < 2) ? usrc : isrc) + (size_t)(g & 1) * E;
    const int* dst = ((g < 2) ? udst : idst) + (size_t)(g & 1) * E;
    const float* elg = el + (size_t)g * N;
    const float* erg = er + (size_t)g * N;
    int* cur = cursor + (size_t)g * N;
    int2* ep = epack + (size_t)g * E;
    for (int i = blockIdx.x * blockDim.x + threadIdx.x; i < E; i += gridDim.x * blockDim.x) {
        int s = src[i], d = dst[i];
        int pos = atomicAdd(&cur[d], 1);
        float e = elg[s] + erg[d];
        e = (e >= 0.f) ? e : 0.2f * e;
        float w = __expf(e);
        ep[pos] = make_int2(s, __float_as_int(w));
    }
}

// wave-per-node: den + weighted aggregate + elu(+b). 4-way unrolled gathers.
__global__ void agg_all(const unsigned short* __restrict__ feat,
                        const float* __restrict__ ub, const float* __restrict__ ib,
                        const int* __restrict__ offsets, const int2* __restrict__ epack,
                        bf16* __restrict__ z, int E, int N) {
    const int g = blockIdx.y;
    const unsigned short* featg = feat + (size_t)g * N * 64;
    const float* bv = ((g < 2) ? ub : ib) + (g & 1) * 64;
    const int* offg = offsets + (size_t)g * (N + 1);
    const int2* ep = epack + (size_t)g * E;
    bf16* zg = z + (size_t)g * N * 64;
    const int lane = threadIdx.x & 63, wave = threadIdx.x >> 6, wpb = blockDim.x >> 6;
    const float bl = bv[lane];
    for (int node = blockIdx.x * wpb + wave; node < N; node += gridDim.x * wpb) {
        int beg = offg[node], end = offg[node + 1];
        float l = 0.f, acc = 0.f;
        int i = beg;
        for (; i + 4 <= end; i += 4) {
            int2 p0 = ep[i], p1 = ep[i + 1], p2 = ep[i + 2], p3 = ep[i + 3];
            unsigned short u0 = featg[(size_t)p0.x * 64 + lane];
            unsigned short u1 = featg[(size_t)p1.x * 64 + lane];
            unsigned short u2 = featg[(size_t)p2.x * 64 + lane];
            unsigned short u3 = featg[(size_t)p3.x * 64 + lane];
            float w0 = __int_as_float(p0.y), w1 = __int_as_float(p1.y);
            float w2 = __int_as_float(p2.y), w3 = __int_as_float(p3.y);
            l += (w0 + w1) + (w2 + w3);
            acc = fmaf(w0, b2f(u0), acc);
            acc = fmaf(w1, b2f(u1), acc);
            acc = fmaf(w2, b2f(u2), acc);
            acc = fmaf(w3, b2f(u3), acc);
        }
        for (; i < end; ++i) {
            int2 p = ep[i];
            float w = __int_as_float(p.y);
            l += w;
            acc = fmaf(w, b2f(featg[(size_t)p.x * 64 + lane]), acc);
        }
        float o = acc / (l + 1e-9f);
        float zz = o + bl;
        zz = (zz > 0.f) ? zz : expm1f(zz);
        zg[(size_t)node * 64 + lane] = (bf16)zz;
    }
}

// wsum[g] += sum_n tanh(z[g,n] @ W1 + b1) @ W2 -- MFMA, z already bf16
__global__ void sem_mfma(const bf16* __restrict__ z,
                         const float* __restrict__ uW1, const float* __restrict__ iW1,
                         const float* __restrict__ ub1, const float* __restrict__ ib1,
                         const float* __restrict__ uW2, const float* __restrict__ iW2,
                         float* __restrict__ wsum, int N) {
    const int g = blockIdx.y, t = g >> 1;
    const float* W1 = t ? iW1 : uW1;
    const float* b1 = t ? ib1 : ub1;
    const float* W2 = t ? iW2 : uW2;
    const int lane = threadIdx.x & 63, wave = threadIdx.x >> 6, wpb = blockDim.x >> 6;
    const int c = lane & 15, q = lane >> 4;
    bf16x8 bfr[8][2];
    #pragma unroll
    for (int nt = 0; nt < 8; ++nt)
        #pragma unroll
        for (int kf = 0; kf < 2; ++kf)
            #pragma unroll
            for (int j = 0; j < 8; ++j)
                bfr[nt][kf][j] = (bf16)W1[(kf * 32 + q * 8 + j) * 128 + nt * 16 + c];
    float b1v[8], w2v[8];
    #pragma unroll
    for (int nt = 0; nt < 8; ++nt) { b1v[nt] = b1[nt * 16 + c]; w2v[nt] = W2[nt * 16 + c]; }
    const bf16* zg = z + (size_t)g * N * 64;
    const f32x4 zf = {0.f, 0.f, 0.f, 0.f};
    float local = 0.f;
    const int tiles = N >> 4;
    for (int tile = blockIdx.x * wpb + wave; tile < tiles; tile += gridDim.x * wpb) {
        const bf16* zr = zg + (size_t)(tile * 16 + c) * 64;
        bf16x8 a0 = *(const bf16x8*)(zr + q * 8);
        bf16x8 a1 = *(const bf16x8*)(zr + 32 + q * 8);
        f32x4 acc[8];
        #pragma unroll
        for (int nt = 0; nt < 8; ++nt) {
            acc[nt] = zf;
            acc[nt] = MFMA16(a0, bfr[nt][0], acc[nt]);
            acc[nt] = MFMA16(a1, bfr[nt][1], acc[nt]);
        }
        #pragma unroll
        for (int nt = 0; nt < 8; ++nt)
            #pragma unroll
            for (int r = 0; r < 4; ++r)
                local += w2v[nt] * fast_tanh(acc[nt][r] + b1v[nt]);
    }
    local = wave_reduce_sum(local);
    if (lane == 0) atomicAdd(&wsum[g], local);
}

// gather + beta-combine + proj + relu + layernorm for indexed rows
__global__ void out_all(const int* __restrict__ uidx, const int* __restrict__ iidx,
                        const int* __restrict__ nidx, const bf16* __restrict__ z,
                        const float* __restrict__ wsum,
                        const float* __restrict__ userW, const float* __restrict__ userb,
                        const float* __restrict__ itemW, const float* __restrict__ itemb,
                        const float* __restrict__ ln_g, const float* __restrict__ ln_b,
                        float* __restrict__ out, int N, int B) {
    const int grp = blockIdx.y;
    const int t = (grp == 0) ? 0 : 1;
    const float* Wt = t ? itemW : userW;
    const float* bt = t ? itemb : userb;
    const int* idx = (grp == 0) ? uidx : ((grp == 1) ? iidx : nidx);
    const bf16* zg = z + (size_t)(t * 2) * N * 64;
    const int lane = threadIdx.x & 63, wave = threadIdx.x >> 6, wpb = blockDim.x >> 6;
    float Wc[64];
    #pragma unroll
    for (int k = 0; k < 64; ++k) Wc[k] = Wt[k * 64 + lane];
    const float btl = bt[lane], gl = ln_g[lane], lbl = ln_b[lane];
    const float invN = 1.f / (float)N;
    float w0 = wsum[t * 2] * invN, w1 = wsum[t * 2 + 1] * invN;
    float mx = fmaxf(w0, w1);
    float e0 = __expf(w0 - mx), e1 = __expf(w1 - mx);
    float bsum = e0 + e1;
    float beta0 = e0 / bsum, beta1 = e1 / bsum;
    for (int r = blockIdx.x * wpb + wave; r < B; r += gridDim.x * wpb) {
        const int urr = __builtin_amdgcn_readfirstlane(r);
        const int un = __builtin_amdgcn_readfirstlane(idx[urr]);
        float e = beta0 * (float)zg[(size_t)un * 64 + lane]
                + beta1 * (float)zg[(size_t)(N + un) * 64 + lane];
        float y = btl;
        #pragma unroll
        for (int k = 0; k < 64; ++k) y = fmaf(__shfl(e, k), Wc[k], y);
        y = fmaxf(y, 0.f);
        float mu = wave_reduce_sum(y) * (1.f / 64.f);
        float d = y - mu;
        float var = wave_reduce_sum(d * d) * (1.f / 64.f);
        out[(size_t)(grp * B + r) * 64 + lane] = gl * d / sqrtf(var + 1e-5f) + lbl;
    }
}

extern "C" void kernel_launch(void* const* d_in, const int* in_sizes, int n_in,
                              void* d_out, int out_size, void* d_ws, size_t ws_size,
                              hipStream_t stream) {
    const int* user_idx = (const int*)d_in[0];
    const int* item_idx = (const int*)d_in[1];
    const int* neg_idx  = (const int*)d_in[2];
    const float* user_feat = (const float*)d_in[3];
    const float* item_feat = (const float*)d_in[4];
    const int* u_src = (const int*)d_in[5];
    const int* u_dst = (const int*)d_in[6];
    const int* i_src = (const int*)d_in[7];
    const int* i_dst = (const int*)d_in[8];
    const float* u_W  = (const float*)d_in[9];
    const float* u_al = (const float*)d_in[10];
    const float* u_ar = (const float*)d_in[11];
    const float* u_b  = (const float*)d_in[12];
    const float* i_W  = (const float*)d_in[13];
    const float* i_al = (const float*)d_in[14];
    const float* i_ar = (const float*)d_in[15];
    const float* i_b  = (const float*)d_in[16];
    const float* u_saW1 = (const float*)d_in[17];
    const float* u_sab1 = (const float*)d_in[18];
    const float* u_saW2 = (const float*)d_in[19];
    const float* i_saW1 = (const float*)d_in[20];
    const float* i_sab1 = (const float*)d_in[21];
    const float* i_saW2 = (const float*)d_in[22];
    const float* userW = (const float*)d_in[23];
    const float* userb = (const float*)d_in[24];
    const float* itemW = (const float*)d_in[25];
    const float* itemb = (const float*)d_in[26];
    const float* ln_g  = (const float*)d_in[27];
    const float* ln_b  = (const float*)d_in[28];

    const int N = N_NODES, E = N_EDGES, B = BATCH;

    char* ws = (char*)d_ws;
    size_t off = 0;
    auto alloc = [&](size_t bytes) -> char* {
        char* p = ws + off;
        off += (bytes + 255) & ~(size_t)255;
        return p;
    };
    bf16* feat   = (bf16*)alloc((size_t)4 * N * 64 * 2);    // 51.2 MB
    bf16* z      = (bf16*)alloc((size_t)4 * N * 64 * 2);    // 51.2 MB
    float* el    = (float*)alloc((size_t)4 * N * 4);
    float* er    = (float*)alloc((size_t)4 * N * 4);
    int* offsets = (int*)alloc((size_t)4 * (N + 1) * 4);
    int* cursor  = (int*)alloc((size_t)4 * N * 4);
    int* counts  = (int*)alloc((size_t)4 * N * 4);
    int2* epack  = (int2*)alloc((size_t)4 * E * 8);         // 16 MB
    int* bsum    = (int*)alloc((size_t)4 * 128 * 4);
    float* wsum  = (float*)alloc(16);
    (void)ws_size; (void)in_sizes; (void)n_in; (void)out_size;

    dim3 blk(256);
    hipMemsetAsync(wsum, 0, 16, stream);
    hipMemsetAsync(counts, 0, (size_t)4 * N * 4, stream);

    feat_mfma<<<dim3(256, 2), blk, 0, stream>>>(user_feat, item_feat, u_W, i_W,
                                                u_al, i_al, u_ar, i_ar, feat, el, er, N);
    hist_all<<<dim3(512, 4), blk, 0, stream>>>(u_dst, i_dst, counts, E, N);
    scanA<<<dim3(NBLK, 4), dim3(1024), 0, stream>>>(counts, offsets, bsum, N);
    scanB<<<dim3(1, 4), dim3(128), 0, stream>>>(bsum, offsets, N);
    scanC<<<dim3(391, 4), blk, 0, stream>>>(offsets, cursor, bsum, N);
    scatter_all<<<dim3(512, 4), blk, 0, stream>>>(u_src, u_dst, i_src, i_dst,
                                                  el, er, cursor, epack, E, N);
    agg_all<<<dim3(2048, 4), blk, 0, stream>>>((const unsigned short*)feat, u_b, i_b,
                                               offsets, epack, z, E, N);
    sem_mfma<<<dim3(256, 4), blk, 0, stream>>>(z, u_saW1, i_saW1, u_sab1, i_sab1,
                                               u_saW2, i_saW2, wsum, N);
    out_all<<<dim3(512, 3), blk, 0, stream>>>(user_idx, item_idx, neg_idx, z, wsum,
                                              userW, userb, itemW, itemb, ln_g, ln_b,
                                              (float*)d_out, N, B);
}